// Round 16
// baseline (122.605 us; speedup 1.0000x reference)
//
#include <hip/hip_runtime.h>
#include <cstdint>
#include <cstddef>

#define N_PTS 4096
#define KDIM  512
#define NFEAT 5
#define NTILES 528   // 32*33/2 upper-triangle 128x128 tiles

typedef __attribute__((ext_vector_type(8))) short bf16x8;   // 8 bf16 = 4 VGPRs
typedef __attribute__((ext_vector_type(4))) float f32x4;
typedef __attribute__((ext_vector_type(4))) unsigned int u32x4;
typedef uint32_t u32;

// round-to-nearest-even fp32 -> bf16 (inputs finite)
__device__ inline unsigned short f2bf(float f) {
  union { float f; u32 u; } v; v.f = f;
  u32 r = (v.u + 0x7fffu + ((v.u >> 16) & 1u)) >> 16;
  return (unsigned short)r;
}

__device__ inline void bf2f2(u32 u, float& a, float& b) {
  union { u32 u; float f; } x, y;
  x.u = u << 16; y.u = u & 0xffff0000u;
  a = x.f; b = y.f;
}

// async global->LDS, 16B per lane (dest is wave-uniform base + lane*16)
__device__ inline void load_lds16(const void* g, void* l) {
  __builtin_amdgcn_global_load_lds(
      (const __attribute__((address_space(1))) void*)g,
      (__attribute__((address_space(3))) void*)l, 16, 0, 0);
}

// ---------------------------------------------------------------------------
// Kernel 1: X (fp32) -> bf16 + per-row squared norms; zeroes gsum
// ---------------------------------------------------------------------------
__global__ __launch_bounds__(256) void prep_kernel(const float* __restrict__ X,
                                                   short* __restrict__ Xb,
                                                   float* __restrict__ sq,
                                                   float* __restrict__ gsum) {
  if (blockIdx.x == 0 && threadIdx.x == 0) *gsum = 0.f;
  const int row = blockIdx.x;
  const int t = threadIdx.x;
  const float2 v = ((const float2*)(X + (size_t)row * KDIM))[t];
  short2 b;
  b.x = (short)f2bf(v.x);
  b.y = (short)f2bf(v.y);
  ((short2*)(Xb + (size_t)row * KDIM))[t] = b;
  float s = v.x * v.x + v.y * v.y;
#pragma unroll
  for (int off = 32; off; off >>= 1) s += __shfl_down(s, off);
  __shared__ float ws[4];
  if ((t & 63) == 0) ws[t >> 6] = s;
  __syncthreads();
  if (t == 0) sq[row] = ws[0] + ws[1] + ws[2] + ws[3];
}

// ---------------------------------------------------------------------------
// Kernel 2: upper-triangle tiles (528 blocks): GEMM (BK=64, XOR-swizzled
// LDS, width-16 global_load_lds) with SIGMA-PERMUTED B staging (r12/r14-
// verified). Output cols c = wave_n*64 + 4*llo + j. Epilogue: fp32 d ->
// weighted distance sum (w=2 off-diag, exact) + bf16 fragment-ordered Dw
// store (17.3 MB, dense, NON-TEMPORAL via ext-vector u32x4).
// ---------------------------------------------------------------------------
__global__ __launch_bounds__(256, 2) void dist_kernel(
    const short* __restrict__ Xb, const float* __restrict__ sq,
    unsigned short* __restrict__ Dw, float* __restrict__ gsum) {
  __shared__ short As[128 * 64];   // 16 KB
  __shared__ short Bs[128 * 64];   // 16 KB
  __shared__ float red[4];

  const int tid = threadIdx.x;
  const int lane = tid & 63;
  const int wid = tid >> 6;
  const int wave_m = wid >> 1, wave_n = wid & 1;
  const int lhi = lane >> 4, llo = lane & 15;
  const int srow = tid >> 3;                 // 0..31
  const int sgran = (tid & 7) ^ (srow & 7);  // XOR-swizzled granule (LDS-keyed)

  // triangular decode: block -> (bm, bn) with bm <= bn
  int t = (int)blockIdx.x;
  int bm = 0;
  while (t >= 32 - bm) { t -= 32 - bm; ++bm; }
  const int bn = bm + t;

  f32x4 acc[4][4];
#pragma unroll
  for (int i = 0; i < 4; ++i)
#pragma unroll
    for (int j = 0; j < 4; ++j) acc[i][j] = (f32x4){0.f, 0.f, 0.f, 0.f};

  // A staging: LDS row g*32+srow <- global row g*32+srow (identity)
  const size_t ga0 = (size_t)(bm * 128 + srow) * KDIM + sgran * 8;
  // B staging: sigma within each 64-half (r12/r14-verified)
  const int sB0 = 4 * (srow & 15) + (srow >> 4);
  const size_t gb0 = (size_t)(bn * 128 + sB0) * KDIM + sgran * 8;      // g even
  const size_t gb1 = (size_t)(bn * 128 + sB0 + 2) * KDIM + sgran * 8;  // g odd

  for (int kt = 0; kt < KDIM / 64; ++kt) {
    const int koff = kt * 64;
#pragma unroll
    for (int g = 0; g < 4; ++g)
      load_lds16(Xb + ga0 + (size_t)g * 32 * KDIM + koff,
                 (char*)As + g * 4096 + tid * 16);
    load_lds16(Xb + gb0 + koff, (char*)Bs + tid * 16);                  // g=0
    load_lds16(Xb + gb1 + koff, (char*)Bs + 4096 + tid * 16);           // g=1
    load_lds16(Xb + gb0 + (size_t)64 * KDIM + koff,
               (char*)Bs + 8192 + tid * 16);                            // g=2
    load_lds16(Xb + gb1 + (size_t)64 * KDIM + koff,
               (char*)Bs + 12288 + tid * 16);                           // g=3
    __syncthreads();

#pragma unroll
    for (int h = 0; h < 2; ++h) {
      bf16x8 a[4], b[4];
#pragma unroll
      for (int i = 0; i < 4; ++i) {
        const int ra = wave_m * 64 + i * 16 + llo;
        const int rb = wave_n * 64 + i * 16 + llo;   // LDS row (permuted content)
        const int c = h * 4 + lhi;
        a[i] = *(const bf16x8*)&As[ra * 64 + ((c ^ (ra & 7)) << 3)];
        b[i] = *(const bf16x8*)&Bs[rb * 64 + ((c ^ (rb & 7)) << 3)];
      }
#pragma unroll
      for (int i = 0; i < 4; ++i)
#pragma unroll
        for (int j = 0; j < 4; ++j)
          acc[i][j] = __builtin_amdgcn_mfma_f32_16x16x32_bf16(
              a[i], b[j], acc[i][j], 0, 0, 0);
    }
    __syncthreads();
  }

  // epilogue: acc[i][j] lane (lhi,llo) reg rr = pair
  //   (row wave_m*64+lhi*4+i*16+rr, col wave_n*64+4*llo+j)
  float lsum = 0.f;
  const int gi0 = bm * 128, gj0 = bn * 128;
  const int r_base = wave_m * 64 + lhi * 4;
  const int c_base = wave_n * 64 + llo * 4;
  const float4 sqjv = *(const float4*)(sq + gj0 + c_base);
  const float sqj[4] = {sqjv.x, sqjv.y, sqjv.z, sqjv.w};

  const size_t tile_base =
      (size_t)blockIdx.x * 16384 + (size_t)wid * 4096;

#pragma unroll
  for (int i = 0; i < 4; ++i) {
    union { unsigned short s[16]; u32x4 q[2]; } pk;
#pragma unroll
    for (int rr = 0; rr < 4; ++rr) {
      const int r = r_base + i * 16 + rr;
      const float sqi = sq[gi0 + r];
#pragma unroll
      for (int j = 0; j < 4; ++j) {
        const int c = c_base + j;                 // local column 0..127
        float d2 = sqi + sqj[j] - 2.f * acc[i][j][rr];
        float dd = sqrtf(fmaxf(d2, 0.f));
        if (gi0 + r == gj0 + c) dd = 0.f;         // exact-zero diagonal
        lsum += dd;
        pk.s[rr * 4 + j] = f2bf(dd);
      }
    }
    unsigned short* dst = Dw + tile_base + (size_t)i * 1024;
    __builtin_nontemporal_store(pk.q[0], (u32x4*)(dst + lane * 8));
    __builtin_nontemporal_store(pk.q[1], (u32x4*)(dst + 512 + lane * 8));
  }

#pragma unroll
  for (int off = 32; off; off >>= 1) lsum += __shfl_down(lsum, off);
  if (lane == 0) red[wid] = lsum;
  __syncthreads();
  if (tid == 0) {
    const float w = (bm == bn) ? 1.f : 2.f;
    atomicAdd(gsum, w * (red[0] + red[1] + red[2] + red[3]));
  }
}

// ---------------------------------------------------------------------------
// Kernel 3: 528 blocks, barrier-free (r14-verified). NT load Dw tile, fast-
// path RBF (1 exp + 2 sqrt), register-direct dual f32x4 NT stores:
// normal = 4x 16B/i (16 llo-lanes -> 256B segments), mirror = 4x 16B/i
// over rr (16 rows x 64B segments). Diagonal tiles skip the mirror.
// All traffic is single-use streaming -> non-temporal hints.
// ---------------------------------------------------------------------------
__global__ __launch_bounds__(256) void rbf_kernel(
    const unsigned short* __restrict__ Dw, const float* __restrict__ gsum,
    const float* __restrict__ mult, float* __restrict__ out) {
  const int tid = threadIdx.x;
  const int lane = tid & 63;
  const int wid = tid >> 6;
  const int wave_m = wid >> 1, wave_n = wid & 1;
  const int lhi = lane >> 4, llo = lane & 15;

  // triangular decode: block -> (bm, bn) with bm <= bn
  int t = (int)blockIdx.x;
  int bm = 0;
  while (t >= 32 - bm) { t -= 32 - bm; ++bm; }
  const int bn = bm + t;
  const bool diag = (bm == bn);

  const float bw = *gsum * (1.0f / ((float)N_PTS * (float)(N_PTS - 1)));
  const float m0 = mult[0], m1 = mult[1], m2 = mult[2], m3 = mult[3],
              m4 = mult[4];
  const bool fast = (m0 == 0.25f && m1 == 0.5f && m2 == 1.0f && m3 == 2.0f &&
                     m4 == 4.0f);
  const float c1 = -1.0f / (bw * m2);   // base coefficient (mult==1)
  float cf[NFEAT];
  cf[0] = -1.0f / (bw * m0); cf[1] = -1.0f / (bw * m1); cf[2] = c1;
  cf[3] = -1.0f / (bw * m3); cf[4] = -1.0f / (bw * m4);

  const size_t tile_base =
      (size_t)blockIdx.x * 16384 + (size_t)wid * 4096;

  // NT load all fragments upfront (hide VMEM latency under exp)
  u32x4 q[4][2];
#pragma unroll
  for (int i = 0; i < 4; ++i) {
    const unsigned short* src = Dw + tile_base + (size_t)i * 1024;
    q[i][0] = __builtin_nontemporal_load((const u32x4*)(src + lane * 8));
    q[i][1] = __builtin_nontemporal_load((const u32x4*)(src + 512 + lane * 8));
  }

  const int gi0 = bm * 128, gj0 = bn * 128;
  const int r_off = wave_m * 64 + lhi * 4;   // + i*16 + rr
  const int c_off = wave_n * 64 + llo * 4;   // + j  (sigma layout)

#pragma unroll
  for (int i = 0; i < 4; ++i) {
    float v[16];
    bf2f2(q[i][0][0], v[0], v[1]);   bf2f2(q[i][0][1], v[2], v[3]);
    bf2f2(q[i][0][2], v[4], v[5]);   bf2f2(q[i][0][3], v[6], v[7]);
    bf2f2(q[i][1][0], v[8], v[9]);   bf2f2(q[i][1][1], v[10], v[11]);
    bf2f2(q[i][1][2], v[12], v[13]); bf2f2(q[i][1][3], v[14], v[15]);

    float o[16];
    if (fast) {
#pragma unroll
      for (int e = 0; e < 16; ++e) {
        const float tt = __expf(v[e] * c1);       // t = exp(-d/bw)
        const float t2 = tt * tt;
        const float t4 = t2 * t2;
        const float s = sqrtf(tt);                // t^(1/2)
        const float qq = sqrtf(s);                // t^(1/4)
        o[e] = t4 + t2 + tt + s + qq;             // diag: d=0 -> exactly 5
      }
    } else {
#pragma unroll
      for (int e = 0; e < 16; ++e) {
        float a = 0.f;
#pragma unroll
        for (int f = 0; f < NFEAT; ++f) a += __expf(v[e] * cf[f]);
        o[e] = a;
      }
    }

    // normal (r,c): one f32x4 per rr (4 consecutive cols), NT
#pragma unroll
    for (int rr = 0; rr < 4; ++rr) {
      float* nrow = out + (size_t)(gi0 + r_off + i * 16 + rr) * N_PTS + gj0 +
                    c_off;
      __builtin_nontemporal_store(
          (f32x4){o[rr * 4 + 0], o[rr * 4 + 1], o[rr * 4 + 2], o[rr * 4 + 3]},
          (f32x4*)nrow);
    }

    // mirror (c,r): one f32x4 per j (4 consecutive rr -> 4 consecutive
    // cols), NT
    if (!diag) {
#pragma unroll
      for (int j = 0; j < 4; ++j) {
        float* mrow = out + (size_t)(gj0 + c_off + j) * N_PTS + gi0 + r_off +
                      i * 16;
        __builtin_nontemporal_store(
            (f32x4){o[j], o[4 + j], o[8 + j], o[12 + j]}, (f32x4*)mrow);
      }
    }
  }
}

extern "C" void kernel_launch(void* const* d_in, const int* in_sizes, int n_in,
                              void* d_out, int out_size, void* d_ws, size_t ws_size,
                              hipStream_t stream) {
  const float* X = (const float*)d_in[0];
  const float* mult = (const float*)d_in[1];
  float* out = (float*)d_out;

  // ws: gsum@0 | sq@1024 (16KB) | Xb@17408 (4MB) | Dw@4211712 (17.3MB bf16)
  char* ws = (char*)d_ws;
  float* gsum = (float*)ws;
  float* sq = (float*)(ws + 1024);
  short* Xb = (short*)(ws + 1024 + N_PTS * sizeof(float));
  unsigned short* Dw = (unsigned short*)(ws + 1024 + N_PTS * sizeof(float) +
                                         (size_t)N_PTS * KDIM * sizeof(short));

  prep_kernel<<<N_PTS, 256, 0, stream>>>(X, Xb, sq, gsum);
  dist_kernel<<<NTILES, 256, 0, stream>>>(Xb, sq, Dw, gsum);
  rbf_kernel<<<NTILES, 256, 0, stream>>>(Dw, gsum, mult, out);
}

// Round 17
// 117.620 us; speedup vs baseline: 1.0424x; 1.0424x over previous
//
#include <hip/hip_runtime.h>
#include <cstdint>
#include <cstddef>

#define N_PTS 4096
#define KDIM  512
#define NFEAT 5
#define NTILES 528   // 32*33/2 upper-triangle 128x128 tiles

typedef __attribute__((ext_vector_type(8))) short bf16x8;   // 8 bf16 = 4 VGPRs
typedef __attribute__((ext_vector_type(4))) float f32x4;
typedef uint32_t u32;

// round-to-nearest-even fp32 -> bf16 (inputs finite)
__device__ inline unsigned short f2bf(float f) {
  union { float f; u32 u; } v; v.f = f;
  u32 r = (v.u + 0x7fffu + ((v.u >> 16) & 1u)) >> 16;
  return (unsigned short)r;
}

__device__ inline void bf2f2(u32 u, float& a, float& b) {
  union { u32 u; float f; } x, y;
  x.u = u << 16; y.u = u & 0xffff0000u;
  a = x.f; b = y.f;
}

// async global->LDS, 16B per lane (dest is wave-uniform base + lane*16)
__device__ inline void load_lds16(const void* g, void* l) {
  __builtin_amdgcn_global_load_lds(
      (const __attribute__((address_space(1))) void*)g,
      (__attribute__((address_space(3))) void*)l, 16, 0, 0);
}

// ---------------------------------------------------------------------------
// Kernel 1: X (fp32) -> bf16 + per-row squared norms; zeroes gsum
// ---------------------------------------------------------------------------
__global__ __launch_bounds__(256) void prep_kernel(const float* __restrict__ X,
                                                   short* __restrict__ Xb,
                                                   float* __restrict__ sq,
                                                   float* __restrict__ gsum) {
  if (blockIdx.x == 0 && threadIdx.x == 0) *gsum = 0.f;
  const int row = blockIdx.x;
  const int t = threadIdx.x;
  const float2 v = ((const float2*)(X + (size_t)row * KDIM))[t];
  short2 b;
  b.x = (short)f2bf(v.x);
  b.y = (short)f2bf(v.y);
  ((short2*)(Xb + (size_t)row * KDIM))[t] = b;
  float s = v.x * v.x + v.y * v.y;
#pragma unroll
  for (int off = 32; off; off >>= 1) s += __shfl_down(s, off);
  __shared__ float ws[4];
  if ((t & 63) == 0) ws[t >> 6] = s;
  __syncthreads();
  if (t == 0) sq[row] = ws[0] + ws[1] + ws[2] + ws[3];
}

// ---------------------------------------------------------------------------
// Kernel 2: upper-triangle tiles (528 blocks): GEMM (BK=64, XOR-swizzled
// LDS, width-16 global_load_lds) with SIGMA-PERMUTED B staging (r12-verified
// mapping: LDS B-row g*32+srow sources global row (g>=2)*64 + 4*(srow&15)
// + 2*(g&1) + (srow>>4); LDS layout/k-swizzle/read addresses untouched).
// Output cols become c = wave_n*64 + 4*llo + j (4 consecutive per fragment).
// Epilogue: fp32 d -> weighted distance sum (w=2 off-diag, exact) + bf16
// fragment-ordered Dw store (17.3 MB, dense uint4). Same (r,c) pair set
// per tile (sigma bijective) -> bw identical up to fp add order.
// NOTE r17: NO non-temporal hints — r16 proved Dw is L2/L3-resident between
// dist and rbf; nt bypass cost +4.5 us (rbf 54-63 us, FETCH from HBM).
// ---------------------------------------------------------------------------
__global__ __launch_bounds__(256, 2) void dist_kernel(
    const short* __restrict__ Xb, const float* __restrict__ sq,
    unsigned short* __restrict__ Dw, float* __restrict__ gsum) {
  __shared__ short As[128 * 64];   // 16 KB
  __shared__ short Bs[128 * 64];   // 16 KB
  __shared__ float red[4];

  const int tid = threadIdx.x;
  const int lane = tid & 63;
  const int wid = tid >> 6;
  const int wave_m = wid >> 1, wave_n = wid & 1;
  const int lhi = lane >> 4, llo = lane & 15;
  const int srow = tid >> 3;                 // 0..31
  const int sgran = (tid & 7) ^ (srow & 7);  // XOR-swizzled granule (LDS-keyed)

  // triangular decode: block -> (bm, bn) with bm <= bn
  int t = (int)blockIdx.x;
  int bm = 0;
  while (t >= 32 - bm) { t -= 32 - bm; ++bm; }
  const int bn = bm + t;

  f32x4 acc[4][4];
#pragma unroll
  for (int i = 0; i < 4; ++i)
#pragma unroll
    for (int j = 0; j < 4; ++j) acc[i][j] = (f32x4){0.f, 0.f, 0.f, 0.f};

  // A staging: LDS row g*32+srow <- global row g*32+srow (identity)
  const size_t ga0 = (size_t)(bm * 128 + srow) * KDIM + sgran * 8;
  // B staging: sigma within each 64-half
  const int sB0 = 4 * (srow & 15) + (srow >> 4);
  const size_t gb0 = (size_t)(bn * 128 + sB0) * KDIM + sgran * 8;      // g even
  const size_t gb1 = (size_t)(bn * 128 + sB0 + 2) * KDIM + sgran * 8;  // g odd

  for (int kt = 0; kt < KDIM / 64; ++kt) {
    const int koff = kt * 64;
#pragma unroll
    for (int g = 0; g < 4; ++g)
      load_lds16(Xb + ga0 + (size_t)g * 32 * KDIM + koff,
                 (char*)As + g * 4096 + tid * 16);
    load_lds16(Xb + gb0 + koff, (char*)Bs + tid * 16);                  // g=0
    load_lds16(Xb + gb1 + koff, (char*)Bs + 4096 + tid * 16);           // g=1
    load_lds16(Xb + gb0 + (size_t)64 * KDIM + koff,
               (char*)Bs + 8192 + tid * 16);                            // g=2
    load_lds16(Xb + gb1 + (size_t)64 * KDIM + koff,
               (char*)Bs + 12288 + tid * 16);                           // g=3
    __syncthreads();

#pragma unroll
    for (int h = 0; h < 2; ++h) {
      bf16x8 a[4], b[4];
#pragma unroll
      for (int i = 0; i < 4; ++i) {
        const int ra = wave_m * 64 + i * 16 + llo;
        const int rb = wave_n * 64 + i * 16 + llo;   // LDS row (permuted content)
        const int c = h * 4 + lhi;
        a[i] = *(const bf16x8*)&As[ra * 64 + ((c ^ (ra & 7)) << 3)];
        b[i] = *(const bf16x8*)&Bs[rb * 64 + ((c ^ (rb & 7)) << 3)];
      }
#pragma unroll
      for (int i = 0; i < 4; ++i)
#pragma unroll
        for (int j = 0; j < 4; ++j)
          acc[i][j] = __builtin_amdgcn_mfma_f32_16x16x32_bf16(
              a[i], b[j], acc[i][j], 0, 0, 0);
    }
    __syncthreads();
  }

  // epilogue: with sigma, acc[i][j] lane (lhi,llo) reg rr = pair
  //   (row wave_m*64+lhi*4+i*16+rr, col wave_n*64+4*llo+j)
  float lsum = 0.f;
  const int gi0 = bm * 128, gj0 = bn * 128;
  const int r_base = wave_m * 64 + lhi * 4;
  const int c_base = wave_n * 64 + llo * 4;
  const float4 sqjv = *(const float4*)(sq + gj0 + c_base);
  const float sqj[4] = {sqjv.x, sqjv.y, sqjv.z, sqjv.w};

  const size_t tile_base =
      (size_t)blockIdx.x * 16384 + (size_t)wid * 4096;

#pragma unroll
  for (int i = 0; i < 4; ++i) {
    union { unsigned short s[16]; uint4 q[2]; } pk;
#pragma unroll
    for (int rr = 0; rr < 4; ++rr) {
      const int r = r_base + i * 16 + rr;
      const float sqi = sq[gi0 + r];
#pragma unroll
      for (int j = 0; j < 4; ++j) {
        const int c = c_base + j;                 // local column 0..127
        float d2 = sqi + sqj[j] - 2.f * acc[i][j][rr];
        float dd = sqrtf(fmaxf(d2, 0.f));
        if (gi0 + r == gj0 + c) dd = 0.f;         // exact-zero diagonal
        lsum += dd;
        pk.s[rr * 4 + j] = f2bf(dd);
      }
    }
    unsigned short* dst = Dw + tile_base + (size_t)i * 1024;
    *(uint4*)(dst + lane * 8) = pk.q[0];
    *(uint4*)(dst + 512 + lane * 8) = pk.q[1];
  }

#pragma unroll
  for (int off = 32; off; off >>= 1) lsum += __shfl_down(lsum, off);
  if (lane == 0) red[wid] = lsum;
  __syncthreads();
  if (tid == 0) {
    const float w = (bm == bn) ? 1.f : 2.f;
    atomicAdd(gsum, w * (red[0] + red[1] + red[2] + red[3]));
  }
}

// ---------------------------------------------------------------------------
// Kernel 3: 528 blocks, BARRIER-FREE. Load Dw tile (dense uint4, L2-hit),
// fast-path RBF (1 exp + 2 sqrt when mult=={.25,.5,1,2,4}), register-direct
// dual float4 stores: normal = 4x float4/i (16 llo-lanes -> 256B segments),
// mirror = 4x float4/i over rr (16 rows x 64B segments). Diagonal tiles
// skip the mirror. No LDS, no syncthreads, no nt hints.
// ---------------------------------------------------------------------------
__global__ __launch_bounds__(256) void rbf_kernel(
    const unsigned short* __restrict__ Dw, const float* __restrict__ gsum,
    const float* __restrict__ mult, float* __restrict__ out) {
  const int tid = threadIdx.x;
  const int lane = tid & 63;
  const int wid = tid >> 6;
  const int wave_m = wid >> 1, wave_n = wid & 1;
  const int lhi = lane >> 4, llo = lane & 15;

  // triangular decode: block -> (bm, bn) with bm <= bn
  int t = (int)blockIdx.x;
  int bm = 0;
  while (t >= 32 - bm) { t -= 32 - bm; ++bm; }
  const int bn = bm + t;
  const bool diag = (bm == bn);

  const float bw = *gsum * (1.0f / ((float)N_PTS * (float)(N_PTS - 1)));
  const float m0 = mult[0], m1 = mult[1], m2 = mult[2], m3 = mult[3],
              m4 = mult[4];
  const bool fast = (m0 == 0.25f && m1 == 0.5f && m2 == 1.0f && m3 == 2.0f &&
                     m4 == 4.0f);
  const float c1 = -1.0f / (bw * m2);   // base coefficient (mult==1)
  float cf[NFEAT];
  cf[0] = -1.0f / (bw * m0); cf[1] = -1.0f / (bw * m1); cf[2] = c1;
  cf[3] = -1.0f / (bw * m3); cf[4] = -1.0f / (bw * m4);

  const size_t tile_base =
      (size_t)blockIdx.x * 16384 + (size_t)wid * 4096;

  // load all fragments upfront (hide VMEM latency under exp)
  uint4 q[4][2];
#pragma unroll
  for (int i = 0; i < 4; ++i) {
    const unsigned short* src = Dw + tile_base + (size_t)i * 1024;
    q[i][0] = *(const uint4*)(src + lane * 8);
    q[i][1] = *(const uint4*)(src + 512 + lane * 8);
  }

  const int gi0 = bm * 128, gj0 = bn * 128;
  const int r_off = wave_m * 64 + lhi * 4;   // + i*16 + rr
  const int c_off = wave_n * 64 + llo * 4;   // + j  (sigma layout)

#pragma unroll
  for (int i = 0; i < 4; ++i) {
    float v[16];
    bf2f2(q[i][0].x, v[0], v[1]);   bf2f2(q[i][0].y, v[2], v[3]);
    bf2f2(q[i][0].z, v[4], v[5]);   bf2f2(q[i][0].w, v[6], v[7]);
    bf2f2(q[i][1].x, v[8], v[9]);   bf2f2(q[i][1].y, v[10], v[11]);
    bf2f2(q[i][1].z, v[12], v[13]); bf2f2(q[i][1].w, v[14], v[15]);

    float o[16];
    if (fast) {
#pragma unroll
      for (int e = 0; e < 16; ++e) {
        const float tt = __expf(v[e] * c1);       // t = exp(-d/bw)
        const float t2 = tt * tt;
        const float t4 = t2 * t2;
        const float s = sqrtf(tt);                // t^(1/2)
        const float qq = sqrtf(s);                // t^(1/4)
        o[e] = t4 + t2 + tt + s + qq;             // diag: d=0 -> exactly 5
      }
    } else {
#pragma unroll
      for (int e = 0; e < 16; ++e) {
        float a = 0.f;
#pragma unroll
        for (int f = 0; f < NFEAT; ++f) a += __expf(v[e] * cf[f]);
        o[e] = a;
      }
    }

    // normal (r,c): one float4 per rr (4 consecutive cols)
#pragma unroll
    for (int rr = 0; rr < 4; ++rr) {
      float* nrow = out + (size_t)(gi0 + r_off + i * 16 + rr) * N_PTS + gj0 +
                    c_off;
      *(float4*)nrow = (float4){o[rr * 4 + 0], o[rr * 4 + 1], o[rr * 4 + 2],
                                o[rr * 4 + 3]};
    }

    // mirror (c,r): one float4 per j (4 consecutive rr -> 4 consecutive cols)
    if (!diag) {
#pragma unroll
      for (int j = 0; j < 4; ++j) {
        float* mrow = out + (size_t)(gj0 + c_off + j) * N_PTS + gi0 + r_off +
                      i * 16;
        *(float4*)mrow = (float4){o[j], o[4 + j], o[8 + j], o[12 + j]};
      }
    }
  }
}

extern "C" void kernel_launch(void* const* d_in, const int* in_sizes, int n_in,
                              void* d_out, int out_size, void* d_ws, size_t ws_size,
                              hipStream_t stream) {
  const float* X = (const float*)d_in[0];
  const float* mult = (const float*)d_in[1];
  float* out = (float*)d_out;

  // ws: gsum@0 | sq@1024 (16KB) | Xb@17408 (4MB) | Dw@4211712 (17.3MB bf16)
  char* ws = (char*)d_ws;
  float* gsum = (float*)ws;
  float* sq = (float*)(ws + 1024);
  short* Xb = (short*)(ws + 1024 + N_PTS * sizeof(float));
  unsigned short* Dw = (unsigned short*)(ws + 1024 + N_PTS * sizeof(float) +
                                         (size_t)N_PTS * KDIM * sizeof(short));

  prep_kernel<<<N_PTS, 256, 0, stream>>>(X, Xb, sq, gsum);
  dist_kernel<<<NTILES, 256, 0, stream>>>(Xb, sq, Dw, gsum);
  rbf_kernel<<<NTILES, 256, 0, stream>>>(Dw, gsum, mult, out);
}